// Round 1
// baseline (260.957 us; speedup 1.0000x reference)
//
#include <hip/hip_runtime.h>

typedef __attribute__((ext_vector_type(8))) short bf16x8;
typedef __attribute__((ext_vector_type(4))) float f32x4;
typedef __attribute__((ext_vector_type(4))) unsigned short u16x4;

// ---------------- helpers ----------------

static __device__ __forceinline__ unsigned short f2bfu(float f) {
  union { float f; unsigned u; } v; v.f = f;
  return (unsigned short)((v.u + 0x7fffu + ((v.u >> 16) & 1u)) >> 16);  // RNE
}

static __device__ __forceinline__ void gload_lds16(const void* g, void* l) {
  // async global->LDS, 16B/lane; LDS dest = wave-uniform base + lane*16
  __builtin_amdgcn_global_load_lds(
      (const __attribute__((address_space(1))) unsigned int*)g,
      (__attribute__((address_space(3))) unsigned int*)l, 16, 0, 0);
}

// ---------------- prep: cast x to bf16 ----------------
__global__ __launch_bounds__(256) void k_cast_bf16(const float* __restrict__ in,
                                                   unsigned short* __restrict__ out) {
  int i = blockIdx.x * 256 + threadIdx.x;          // grid covers exactly n/4
  float4 v = ((const float4*)in)[i];
  u16x4 o = { f2bfu(v.x), f2bfu(v.y), f2bfu(v.z), f2bfu(v.w) };
  *(u16x4*)(out + (size_t)i * 4) = o;
}

// ---------------- prep: per-expert transpose+convert ----------------
// in:  f32  [z][R][C]   out: bf16 at  out + z*eoff + c*ostride + r
__global__ __launch_bounds__(256) void k_transpose_bf16(const float* __restrict__ in,
                                                        unsigned short* __restrict__ out,
                                                        int R, int C, int ostride, long eoff) {
  __shared__ float tile[32][33];
  int z = blockIdx.z;
  int c0 = blockIdx.x * 32, r0 = blockIdx.y * 32;
  const float* src = in + (size_t)z * R * C;
  unsigned short* dst = out + (size_t)z * eoff;
  int tx = threadIdx.x & 31, ty = threadIdx.x >> 5;   // 32 x 8
#pragma unroll
  for (int i = 0; i < 32; i += 8)
    tile[ty + i][tx] = src[(size_t)(r0 + ty + i) * C + (c0 + tx)];
  __syncthreads();
#pragma unroll
  for (int i = 0; i < 32; i += 8)
    dst[(size_t)(c0 + ty + i) * ostride + (r0 + tx)] = f2bfu(tile[tx][ty + i]);
}

// ---------------- router: logits, softmax-top8, combine weights ----------------
__global__ __launch_bounds__(64) void k_router(const float* __restrict__ x,
                                               const float* __restrict__ gw,
                                               float* __restrict__ combine,
                                               float* __restrict__ logits) {
  int t = blockIdx.x;
  int lane = threadIdx.x;
  const float* xr = x + (size_t)t * 1024;
  float acc[16];
#pragma unroll
  for (int e = 0; e < 16; ++e) acc[e] = 0.f;
  for (int h = lane; h < 1024; h += 64) {
    float xv = xr[h];
    const float4* gr = (const float4*)(gw + (size_t)h * 16);
#pragma unroll
    for (int q = 0; q < 4; ++q) {
      float4 g4 = gr[q];
      acc[q * 4 + 0] += xv * g4.x;
      acc[q * 4 + 1] += xv * g4.y;
      acc[q * 4 + 2] += xv * g4.z;
      acc[q * 4 + 3] += xv * g4.w;
    }
  }
#pragma unroll
  for (int e = 0; e < 16; ++e) {
#pragma unroll
    for (int off = 32; off > 0; off >>= 1)
      acc[e] += __shfl_xor(acc[e], off);
  }
  if (lane < 16) logits[(size_t)t * 16 + lane] = acc[lane];

  // top-8 of logits == top-8 of softmax (monotone); renormalized weights
  float m = acc[0];
#pragma unroll
  for (int e = 1; e < 16; ++e) m = fmaxf(m, acc[e]);
  unsigned sel = 0u;
  for (int k = 0; k < 8; ++k) {
    float best = -3.4e38f; int bi = 0;
#pragma unroll
    for (int e = 0; e < 16; ++e)
      if (!((sel >> e) & 1u) && acc[e] > best) { best = acc[e]; bi = e; }
    sel |= 1u << bi;
  }
  float s = 0.f;
#pragma unroll
  for (int e = 0; e < 16; ++e)
    if ((sel >> e) & 1u) s += expf(acc[e] - m);
  float inv = 1.f / s;
  if (lane < 16)
    combine[(size_t)t * 16 + lane] = ((sel >> lane) & 1u) ? expf(acc[lane] - m) * inv : 0.f;
}

// ---------------- fused gate+up GEMM ----------------
// mid[t][e*512+i] = bf16( silu(x@wg)[t][i] * (x@wu)[t][i] * combine[t][e] )
// BM=128 (tokens), BN=64 (i), BK=32.  4 waves: wave tile 64x32, acc 4x2 frags x2 mats.
// LDS XOR swizzle: 16B slot p of row r holds logical k-slot p ^ ((r>>1)&3).
__global__ __launch_bounds__(256) void k_gateup(const unsigned short* __restrict__ xb,
                                                const unsigned short* __restrict__ wgt,
                                                const unsigned short* __restrict__ wut,
                                                const float* __restrict__ combine,
                                                unsigned short* __restrict__ mids) {
  __shared__ alignas(16) char lds[16384];
  char* sA  = lds;           // 128x32 bf16 (rows = tokens), 64B rows
  char* sBg = lds + 8192;    // 64x32 (rows = i)
  char* sBu = lds + 12288;

  const int e  = blockIdx.z;
  const int m0 = blockIdx.x * 128;
  const int i0 = blockIdx.y * 64;
  const int tid = threadIdx.x;
  const int lane = tid & 63;
  const int w = tid >> 6;
  const int wm = (w >> 1) * 64;
  const int wn = (w & 1) * 32;

  const unsigned short* wg = wgt + (size_t)e * (512 * 1024);
  const unsigned short* wu = wut + (size_t)e * (512 * 1024);

  // staging: w0 -> A rows 0-63, w1 -> A rows 64-127, w2 -> Bg, w3 -> Bu (4 x 1KB each)
  const unsigned short* sb;
  char* db;
  if (w == 0)      { sb = xb + (size_t)m0 * 1024;        db = sA;        }
  else if (w == 1) { sb = xb + (size_t)(m0 + 64) * 1024; db = sA + 4096; }
  else if (w == 2) { sb = wg + (size_t)i0 * 1024;        db = sBg;       }
  else             { sb = wu + (size_t)i0 * 1024;        db = sBu;       }
  const int srow = lane >> 2;                       // row within 16-row chunk
  const int slog = (lane & 3) ^ ((srow >> 1) & 3);  // pre-swizzled source slot
  const unsigned short* sg = sb + (size_t)srow * 1024 + slog * 8;

  const int r0 = lane & 15;
  const int gp16 = ((lane >> 4) ^ ((r0 >> 1) & 3)) << 4;  // swizzled read slot (bytes)
  const char* ap  = sA  + ((wm + r0) << 6) + gp16;
  const char* bgp = sBg + ((wn + r0) << 6) + gp16;
  const char* bup = sBu + ((wn + r0) << 6) + gp16;

  f32x4 accg[4][2], accu[4][2];
#pragma unroll
  for (int fm = 0; fm < 4; ++fm)
#pragma unroll
    for (int fn = 0; fn < 2; ++fn) {
      accg[fm][fn] = f32x4{0.f, 0.f, 0.f, 0.f};
      accu[fm][fn] = f32x4{0.f, 0.f, 0.f, 0.f};
    }

  for (int k0 = 0; k0 < 1024; k0 += 32) {
#pragma unroll
    for (int j = 0; j < 4; ++j)
      gload_lds16(sg + k0 + (size_t)j * (16 * 1024), db + j * 1024);
    __syncthreads();
    bf16x8 a[4], bg[2], bu[2];
#pragma unroll
    for (int fm = 0; fm < 4; ++fm) a[fm] = *(const bf16x8*)(ap + fm * 1024);
#pragma unroll
    for (int fn = 0; fn < 2; ++fn) {
      bg[fn] = *(const bf16x8*)(bgp + fn * 1024);
      bu[fn] = *(const bf16x8*)(bup + fn * 1024);
    }
#pragma unroll
    for (int fm = 0; fm < 4; ++fm)
#pragma unroll
      for (int fn = 0; fn < 2; ++fn) {
        accg[fm][fn] = __builtin_amdgcn_mfma_f32_16x16x32_bf16(a[fm], bg[fn], accg[fm][fn], 0, 0, 0);
        accu[fm][fn] = __builtin_amdgcn_mfma_f32_16x16x32_bf16(a[fm], bu[fn], accu[fm][fn], 0, 0, 0);
      }
    __syncthreads();
  }

  const int gq = lane >> 4;
#pragma unroll
  for (int fm = 0; fm < 4; ++fm) {
    float cw[4];
#pragma unroll
    for (int jj = 0; jj < 4; ++jj)
      cw[jj] = combine[(size_t)(m0 + wm + fm * 16 + gq * 4 + jj) * 16 + e];
#pragma unroll
    for (int fn = 0; fn < 2; ++fn)
#pragma unroll
      for (int jj = 0; jj < 4; ++jj) {
        float gv = accg[fm][fn][jj];
        float uv = accu[fm][fn][jj];
        float mv = gv / (1.f + __expf(-gv)) * uv * cw[jj];
        int mrow = m0 + wm + fm * 16 + gq * 4 + jj;
        int mcol = e * 512 + i0 + wn + fn * 16 + r0;
        mids[(size_t)mrow * 8192 + mcol] = f2bfu(mv);
      }
  }
}

// ---------------- down GEMM: out[2048,1024] = mid[2048,8192] @ WD ----------------
// WD staged from wdt[h][k] (K-major). BM=128, BN=64, BK=32, grid 16x16 = 256 blocks.
__global__ __launch_bounds__(256) void k_down(const unsigned short* __restrict__ mids,
                                              const unsigned short* __restrict__ wdt,
                                              float* __restrict__ out) {
  __shared__ alignas(16) char lds[12288];
  char* sA = lds;          // 128x32
  char* sB = lds + 8192;   // 64x32

  const int m0 = blockIdx.x * 128;
  const int h0 = blockIdx.y * 64;
  const int tid = threadIdx.x;
  const int lane = tid & 63;
  const int w = tid >> 6;
  const int wm = (w >> 1) * 64;
  const int wn = (w & 1) * 32;

  const unsigned short* sb = nullptr;
  char* db = nullptr;
  if (w == 0)      { sb = mids + (size_t)m0 * 8192;        db = sA;        }
  else if (w == 1) { sb = mids + (size_t)(m0 + 64) * 8192; db = sA + 4096; }
  else if (w == 2) { sb = wdt + (size_t)h0 * 8192;         db = sB;        }
  const int srow = lane >> 2;
  const int slog = (lane & 3) ^ ((srow >> 1) & 3);
  const unsigned short* sg = sb ? (sb + (size_t)srow * 8192 + slog * 8) : nullptr;

  const int r0 = lane & 15;
  const int gp16 = ((lane >> 4) ^ ((r0 >> 1) & 3)) << 4;
  const char* ap = sA + ((wm + r0) << 6) + gp16;
  const char* bp = sB + ((wn + r0) << 6) + gp16;

  f32x4 acc[4][2];
#pragma unroll
  for (int fm = 0; fm < 4; ++fm)
#pragma unroll
    for (int fn = 0; fn < 2; ++fn) acc[fm][fn] = f32x4{0.f, 0.f, 0.f, 0.f};

  for (int k0 = 0; k0 < 8192; k0 += 32) {
    if (sb) {
#pragma unroll
      for (int j = 0; j < 4; ++j)
        gload_lds16(sg + k0 + (size_t)j * (16 * 8192), db + j * 1024);
    }
    __syncthreads();
    bf16x8 a[4], b[2];
#pragma unroll
    for (int fm = 0; fm < 4; ++fm) a[fm] = *(const bf16x8*)(ap + fm * 1024);
#pragma unroll
    for (int fn = 0; fn < 2; ++fn) b[fn] = *(const bf16x8*)(bp + fn * 1024);
#pragma unroll
    for (int fm = 0; fm < 4; ++fm)
#pragma unroll
      for (int fn = 0; fn < 2; ++fn)
        acc[fm][fn] = __builtin_amdgcn_mfma_f32_16x16x32_bf16(a[fm], b[fn], acc[fm][fn], 0, 0, 0);
    __syncthreads();
  }

  const int gq = lane >> 4;
#pragma unroll
  for (int fm = 0; fm < 4; ++fm)
#pragma unroll
    for (int fn = 0; fn < 2; ++fn)
#pragma unroll
      for (int jj = 0; jj < 4; ++jj)
        out[(size_t)(m0 + wm + fm * 16 + gq * 4 + jj) * 1024 + (h0 + wn + fn * 16 + r0)] =
            acc[fm][fn][jj];
}

// ---------------- launch ----------------
extern "C" void kernel_launch(void* const* d_in, const int* in_sizes, int n_in,
                              void* d_out, int out_size, void* d_ws, size_t ws_size,
                              hipStream_t stream) {
  const float* x   = (const float*)d_in[0];  // [2048,1024]
  const float* gw  = (const float*)d_in[1];  // [1024,16]
  const float* wga = (const float*)d_in[2];  // [16,1024,512]
  const float* wup = (const float*)d_in[3];  // [16,1024,512]
  const float* wdo = (const float*)d_in[4];  // [16,512,1024]
  float* out = (float*)d_out;                       // [2048,1024]
  float* logits = out + (size_t)2048 * 1024;        // [2048,16]

  char* ws = (char*)d_ws;
  unsigned short* xb   = (unsigned short*)(ws + 0);         //  4 MB  x bf16
  unsigned short* wgt  = (unsigned short*)(ws + 4194304);   // 16 MB  [E][I][H]
  unsigned short* wut  = (unsigned short*)(ws + 20971520);  // 16 MB  [E][I][H]
  unsigned short* wdt  = (unsigned short*)(ws + 37748736);  // 16 MB  [H][E*I]
  unsigned short* mids = (unsigned short*)(ws + 54525952);  // 32 MB  [T][E*I]
  float* combine       = (float*)(ws + 88080384);           // 128 KB [T][E]

  k_cast_bf16<<<2048, 256, 0, stream>>>(x, xb);
  k_transpose_bf16<<<dim3(16, 32, 16), 256, 0, stream>>>(wga, wgt, 1024, 512, 1024, 524288L);
  k_transpose_bf16<<<dim3(16, 32, 16), 256, 0, stream>>>(wup, wut, 1024, 512, 1024, 524288L);
  k_transpose_bf16<<<dim3(32, 16, 16), 256, 0, stream>>>(wdo, wdt, 512, 1024, 8192, 512L);
  k_router<<<2048, 64, 0, stream>>>(x, gw, combine, logits);
  k_gateup<<<dim3(16, 8, 16), 256, 0, stream>>>(xb, wgt, wut, combine, mids);
  k_down<<<dim3(16, 16), 256, 0, stream>>>(mids, wdt, out);
}

// Round 2
// 209.600 us; speedup vs baseline: 1.2450x; 1.2450x over previous
//
#include <hip/hip_runtime.h>

typedef __attribute__((ext_vector_type(8))) short bf16x8;
typedef __attribute__((ext_vector_type(4))) float f32x4;
typedef __attribute__((ext_vector_type(4))) unsigned short u16x4;

// ---------------- helpers ----------------

static __device__ __forceinline__ unsigned short f2bfu(float f) {
  union { float f; unsigned u; } v; v.f = f;
  return (unsigned short)((v.u + 0x7fffu + ((v.u >> 16) & 1u)) >> 16);  // RNE
}

static __device__ __forceinline__ void gload_lds16(const void* g, void* l) {
  // async global->LDS, 16B/lane; LDS dest = wave-uniform base + lane*16
  __builtin_amdgcn_global_load_lds(
      (const __attribute__((address_space(1))) unsigned int*)g,
      (__attribute__((address_space(3))) unsigned int*)l, 16, 0, 0);
}

// ---------------- prep: cast x to bf16 ----------------
__global__ __launch_bounds__(256) void k_cast_bf16(const float* __restrict__ in,
                                                   unsigned short* __restrict__ out) {
  int i = blockIdx.x * 256 + threadIdx.x;          // grid covers exactly n/4
  float4 v = ((const float4*)in)[i];
  u16x4 o = { f2bfu(v.x), f2bfu(v.y), f2bfu(v.z), f2bfu(v.w) };
  *(u16x4*)(out + (size_t)i * 4) = o;
}

// ---------------- prep: per-expert transpose+convert ----------------
// in:  f32  [z][R][C]   out: bf16 at  out + z*eoff + c*ostride + r
__global__ __launch_bounds__(256) void k_transpose_bf16(const float* __restrict__ in,
                                                        unsigned short* __restrict__ out,
                                                        int R, int C, int ostride, long eoff) {
  __shared__ float tile[32][33];
  int z = blockIdx.z;
  int c0 = blockIdx.x * 32, r0 = blockIdx.y * 32;
  const float* src = in + (size_t)z * R * C;
  unsigned short* dst = out + (size_t)z * eoff;
  int tx = threadIdx.x & 31, ty = threadIdx.x >> 5;   // 32 x 8
#pragma unroll
  for (int i = 0; i < 32; i += 8)
    tile[ty + i][tx] = src[(size_t)(r0 + ty + i) * C + (c0 + tx)];
  __syncthreads();
#pragma unroll
  for (int i = 0; i < 32; i += 8)
    dst[(size_t)(c0 + ty + i) * ostride + (r0 + tx)] = f2bfu(tile[tx][ty + i]);
}

// ---------------- router: logits, softmax-top8, combine weights ----------------
__global__ __launch_bounds__(64) void k_router(const float* __restrict__ x,
                                               const float* __restrict__ gw,
                                               float* __restrict__ combine,
                                               float* __restrict__ logits) {
  int t = blockIdx.x;
  int lane = threadIdx.x;
  const float* xr = x + (size_t)t * 1024;
  float acc[16];
#pragma unroll
  for (int e = 0; e < 16; ++e) acc[e] = 0.f;
  for (int h = lane; h < 1024; h += 64) {
    float xv = xr[h];
    const float4* gr = (const float4*)(gw + (size_t)h * 16);
#pragma unroll
    for (int q = 0; q < 4; ++q) {
      float4 g4 = gr[q];
      acc[q * 4 + 0] += xv * g4.x;
      acc[q * 4 + 1] += xv * g4.y;
      acc[q * 4 + 2] += xv * g4.z;
      acc[q * 4 + 3] += xv * g4.w;
    }
  }
#pragma unroll
  for (int e = 0; e < 16; ++e) {
#pragma unroll
    for (int off = 32; off > 0; off >>= 1)
      acc[e] += __shfl_xor(acc[e], off);
  }
  if (lane < 16) logits[(size_t)t * 16 + lane] = acc[lane];

  // top-8 of logits == top-8 of softmax (monotone); renormalized weights
  float m = acc[0];
#pragma unroll
  for (int e = 1; e < 16; ++e) m = fmaxf(m, acc[e]);
  unsigned sel = 0u;
  for (int k = 0; k < 8; ++k) {
    float best = -3.4e38f; int bi = 0;
#pragma unroll
    for (int e = 0; e < 16; ++e)
      if (!((sel >> e) & 1u) && acc[e] > best) { best = acc[e]; bi = e; }
    sel |= 1u << bi;
  }
  float s = 0.f;
#pragma unroll
  for (int e = 0; e < 16; ++e)
    if ((sel >> e) & 1u) s += expf(acc[e] - m);
  float inv = 1.f / s;
  if (lane < 16)
    combine[(size_t)t * 16 + lane] = ((sel >> lane) & 1u) ? expf(acc[lane] - m) * inv : 0.f;
}

// ---------------- fused gate+up GEMM ----------------
// mid[t][e*512+i] = bf16( silu(x@wg)[t][i] * (x@wu)[t][i] * combine[t][e] )
// BM=128 (tokens), BN=64 (i), BK=32.  4 waves: wave tile 64x32, acc 4x2 frags x2 mats.
// LDS XOR swizzle: 16B slot p of row r holds logical k-slot p ^ ((r>>1)&3).
__global__ __launch_bounds__(256) void k_gateup(const unsigned short* __restrict__ xb,
                                                const unsigned short* __restrict__ wgt,
                                                const unsigned short* __restrict__ wut,
                                                const float* __restrict__ combine,
                                                unsigned short* __restrict__ mids) {
  __shared__ alignas(16) char lds[16384];
  char* sA  = lds;           // 128x32 bf16 (rows = tokens), 64B rows
  char* sBg = lds + 8192;    // 64x32 (rows = i)
  char* sBu = lds + 12288;

  const int e  = blockIdx.z;
  const int m0 = blockIdx.x * 128;
  const int i0 = blockIdx.y * 64;
  const int tid = threadIdx.x;
  const int lane = tid & 63;
  const int w = tid >> 6;
  const int wm = (w >> 1) * 64;
  const int wn = (w & 1) * 32;

  const unsigned short* wg = wgt + (size_t)e * (512 * 1024);
  const unsigned short* wu = wut + (size_t)e * (512 * 1024);

  // staging: w0 -> A rows 0-63, w1 -> A rows 64-127, w2 -> Bg, w3 -> Bu (4 x 1KB each)
  const unsigned short* sb;
  char* db;
  if (w == 0)      { sb = xb + (size_t)m0 * 1024;        db = sA;        }
  else if (w == 1) { sb = xb + (size_t)(m0 + 64) * 1024; db = sA + 4096; }
  else if (w == 2) { sb = wg + (size_t)i0 * 1024;        db = sBg;       }
  else             { sb = wu + (size_t)i0 * 1024;        db = sBu;       }
  const int srow = lane >> 2;                       // row within 16-row chunk
  const int slog = (lane & 3) ^ ((srow >> 1) & 3);  // pre-swizzled source slot
  const unsigned short* sg = sb + (size_t)srow * 1024 + slog * 8;

  const int r0 = lane & 15;
  const int gp16 = ((lane >> 4) ^ ((r0 >> 1) & 3)) << 4;  // swizzled read slot (bytes)
  const char* ap  = sA  + ((wm + r0) << 6) + gp16;
  const char* bgp = sBg + ((wn + r0) << 6) + gp16;
  const char* bup = sBu + ((wn + r0) << 6) + gp16;

  f32x4 accg[4][2], accu[4][2];
#pragma unroll
  for (int fm = 0; fm < 4; ++fm)
#pragma unroll
    for (int fn = 0; fn < 2; ++fn) {
      accg[fm][fn] = f32x4{0.f, 0.f, 0.f, 0.f};
      accu[fm][fn] = f32x4{0.f, 0.f, 0.f, 0.f};
    }

  for (int k0 = 0; k0 < 1024; k0 += 32) {
#pragma unroll
    for (int j = 0; j < 4; ++j)
      gload_lds16(sg + k0 + (size_t)j * (16 * 1024), db + j * 1024);
    __syncthreads();
    bf16x8 a[4], bg[2], bu[2];
#pragma unroll
    for (int fm = 0; fm < 4; ++fm) a[fm] = *(const bf16x8*)(ap + fm * 1024);
#pragma unroll
    for (int fn = 0; fn < 2; ++fn) {
      bg[fn] = *(const bf16x8*)(bgp + fn * 1024);
      bu[fn] = *(const bf16x8*)(bup + fn * 1024);
    }
#pragma unroll
    for (int fm = 0; fm < 4; ++fm)
#pragma unroll
      for (int fn = 0; fn < 2; ++fn) {
        accg[fm][fn] = __builtin_amdgcn_mfma_f32_16x16x32_bf16(a[fm], bg[fn], accg[fm][fn], 0, 0, 0);
        accu[fm][fn] = __builtin_amdgcn_mfma_f32_16x16x32_bf16(a[fm], bu[fn], accu[fm][fn], 0, 0, 0);
      }
    __syncthreads();
  }

  const int gq = lane >> 4;
#pragma unroll
  for (int fm = 0; fm < 4; ++fm) {
    float cw[4];
#pragma unroll
    for (int jj = 0; jj < 4; ++jj)
      cw[jj] = combine[(size_t)(m0 + wm + fm * 16 + gq * 4 + jj) * 16 + e];
#pragma unroll
    for (int fn = 0; fn < 2; ++fn)
#pragma unroll
      for (int jj = 0; jj < 4; ++jj) {
        float gv = accg[fm][fn][jj];
        float uv = accu[fm][fn][jj];
        float mv = gv / (1.f + __expf(-gv)) * uv * cw[jj];
        int mrow = m0 + wm + fm * 16 + gq * 4 + jj;
        int mcol = e * 512 + i0 + wn + fn * 16 + r0;
        mids[(size_t)mrow * 8192 + mcol] = f2bfu(mv);
      }
  }
}

// ---------------- down GEMM, split-K: part[z] = mid[:, z*2048:(z+1)*2048] @ WD[z slice]
// WD staged from wdt[h][k] (K-major). BM=128, BN=64, BK=32, grid 16x16x4 = 1024 blocks.
__global__ __launch_bounds__(256) void k_down(const unsigned short* __restrict__ mids,
                                              const unsigned short* __restrict__ wdt,
                                              float* __restrict__ part) {
  __shared__ alignas(16) char lds[12288];
  char* sA = lds;          // 128x32
  char* sB = lds + 8192;   // 64x32

  const int m0 = blockIdx.x * 128;
  const int h0 = blockIdx.y * 64;
  const int kz = blockIdx.z;             // split-K slice: K in [kz*2048, kz*2048+2048)
  const int tid = threadIdx.x;
  const int lane = tid & 63;
  const int w = tid >> 6;
  const int wm = (w >> 1) * 64;
  const int wn = (w & 1) * 32;

  const unsigned short* sb = nullptr;
  char* db = nullptr;
  if (w == 0)      { sb = mids + (size_t)m0 * 8192;        db = sA;        }
  else if (w == 1) { sb = mids + (size_t)(m0 + 64) * 8192; db = sA + 4096; }
  else if (w == 2) { sb = wdt + (size_t)h0 * 8192;         db = sB;        }
  const int srow = lane >> 2;
  const int slog = (lane & 3) ^ ((srow >> 1) & 3);
  const unsigned short* sg = sb ? (sb + (size_t)srow * 8192 + slog * 8) : nullptr;

  const int r0 = lane & 15;
  const int gp16 = ((lane >> 4) ^ ((r0 >> 1) & 3)) << 4;
  const char* ap = sA + ((wm + r0) << 6) + gp16;
  const char* bp = sB + ((wn + r0) << 6) + gp16;

  f32x4 acc[4][2];
#pragma unroll
  for (int fm = 0; fm < 4; ++fm)
#pragma unroll
    for (int fn = 0; fn < 2; ++fn) acc[fm][fn] = f32x4{0.f, 0.f, 0.f, 0.f};

  const int kbeg = kz * 2048, kend = kbeg + 2048;
  for (int k0 = kbeg; k0 < kend; k0 += 32) {
    if (sb) {
#pragma unroll
      for (int j = 0; j < 4; ++j)
        gload_lds16(sg + k0 + (size_t)j * (16 * 8192), db + j * 1024);
    }
    __syncthreads();
    bf16x8 a[4], b[2];
#pragma unroll
    for (int fm = 0; fm < 4; ++fm) a[fm] = *(const bf16x8*)(ap + fm * 1024);
#pragma unroll
    for (int fn = 0; fn < 2; ++fn) b[fn] = *(const bf16x8*)(bp + fn * 1024);
#pragma unroll
    for (int fm = 0; fm < 4; ++fm)
#pragma unroll
      for (int fn = 0; fn < 2; ++fn)
        acc[fm][fn] = __builtin_amdgcn_mfma_f32_16x16x32_bf16(a[fm], b[fn], acc[fm][fn], 0, 0, 0);
    __syncthreads();
  }

  float* pout = part + (size_t)kz * (2048 * 1024);
  const int gq = lane >> 4;
#pragma unroll
  for (int fm = 0; fm < 4; ++fm)
#pragma unroll
    for (int fn = 0; fn < 2; ++fn)
#pragma unroll
      for (int jj = 0; jj < 4; ++jj)
        pout[(size_t)(m0 + wm + fm * 16 + gq * 4 + jj) * 1024 + (h0 + wn + fn * 16 + r0)] =
            acc[fm][fn][jj];
}

// ---------------- reduce 4 split-K slices ----------------
__global__ __launch_bounds__(256) void k_reduce(const float* __restrict__ part,
                                                float* __restrict__ out) {
  int i = blockIdx.x * 256 + threadIdx.x;          // float4 index; grid covers 2048*1024/4
  const float4* p = (const float4*)part;
  float4 a = p[i];
  float4 b = p[i + 524288];
  float4 c = p[i + 2 * 524288];
  float4 d = p[i + 3 * 524288];
  float4 s = { a.x + b.x + c.x + d.x, a.y + b.y + c.y + d.y,
               a.z + b.z + c.z + d.z, a.w + b.w + c.w + d.w };
  ((float4*)out)[i] = s;
}

// ---------------- launch ----------------
extern "C" void kernel_launch(void* const* d_in, const int* in_sizes, int n_in,
                              void* d_out, int out_size, void* d_ws, size_t ws_size,
                              hipStream_t stream) {
  const float* x   = (const float*)d_in[0];  // [2048,1024]
  const float* gw  = (const float*)d_in[1];  // [1024,16]
  const float* wga = (const float*)d_in[2];  // [16,1024,512]
  const float* wup = (const float*)d_in[3];  // [16,1024,512]
  const float* wdo = (const float*)d_in[4];  // [16,512,1024]
  float* out = (float*)d_out;                       // [2048,1024]
  float* logits = out + (size_t)2048 * 1024;        // [2048,16]

  char* ws = (char*)d_ws;
  unsigned short* xb   = (unsigned short*)(ws + 0);         //  4 MB  x bf16
  unsigned short* wgt  = (unsigned short*)(ws + 4194304);   // 16 MB  [E][I][H]
  unsigned short* wut  = (unsigned short*)(ws + 20971520);  // 16 MB  [E][I][H]
  unsigned short* wdt  = (unsigned short*)(ws + 37748736);  // 16 MB  [H][E*I]
  unsigned short* mids = (unsigned short*)(ws + 54525952);  // 32 MB  [T][E*I]
  float* combine       = (float*)(ws + 88080384);           // 128 KB [T][E]
  // split-K partials (32 MB) reuse the wgt/wut region — dead once k_gateup is done
  float* part          = (float*)(ws + 4194304);            // [4][2048][1024] f32

  k_cast_bf16<<<2048, 256, 0, stream>>>(x, xb);
  k_transpose_bf16<<<dim3(16, 32, 16), 256, 0, stream>>>(wga, wgt, 1024, 512, 1024, 524288L);
  k_transpose_bf16<<<dim3(16, 32, 16), 256, 0, stream>>>(wup, wut, 1024, 512, 1024, 524288L);
  k_transpose_bf16<<<dim3(32, 16, 16), 256, 0, stream>>>(wdo, wdt, 512, 1024, 8192, 512L);
  k_router<<<2048, 64, 0, stream>>>(x, gw, combine, logits);
  k_gateup<<<dim3(16, 8, 16), 256, 0, stream>>>(xb, wgt, wut, combine, mids);
  k_down<<<dim3(16, 16, 4), 256, 0, stream>>>(mids, wdt, part);
  k_reduce<<<2048, 256, 0, stream>>>(part, out);
}